// Round 4
// baseline (122.169 us; speedup 1.0000x reference)
//
#include <hip/hip_runtime.h>

// QueryAndGroup: ball query (first 32 idx within radius, index order, padded
// with first hit) + grouped_xyz (xyz[idx]-center) + grouped feature gather.
// Shapes: xyz (8,16384,3) f32, new_xyz (8,1024,3) f32, features (8,64,16384) f32
// Out: (8, 3+64, 1024, 32) f32.
//
// R4: (a) query scan software-pipelined — prefetch next 512-pt chunk's raw
// coords before ballot-processing the current chunk (overlap L2 latency with
// VALU); (b) gather restructured to wave-autonomous 64-thread blocks, no
// barriers; (c) transpose unchanged (HBM-bound, ~11us). Kernel-side budget
// ~40us of the 120us dur (rest is harness poison/restore fills, 44us each).

#define BB 8
#define NN 16384
#define SS 1024
#define CC 64
#define NSAMP 32
#define OUTCH (3 + CC)

// float(0.04) to match numpy's weak-scalar promotion (NOT 0.2f*0.2f).
#define R2 0.04f

// ---------------- merged kernel A: transpose + ball query ----------------
// blocks [0, 2048): transpose one (b, 64ch, 64pt) tile of feats -> (B,N,C)
// blocks [2048, 4096): 4 ball queries (one per wave)
__global__ __launch_bounds__(256) void prep_kernel(
    const float* __restrict__ xyz,      // (B,N,3)
    const float* __restrict__ new_xyz,  // (B,S,3)
    const float* __restrict__ feats,    // (B,C,N)
    float* __restrict__ ftr,            // ws: (B,N,C)
    int* __restrict__ idxq,             // ws: (B*S,32)
    float* __restrict__ out)            // (B,67,S,32)
{
    __shared__ float tile[64][65];      // transpose tile (65-pad: <=2-way)
    __shared__ int sidx[4][NSAMP];

    const int t = threadIdx.x;
    if (blockIdx.x < 2048) {
        // ---- transpose (B,C,N) -> (B,N,C), float4 on both global sides ----
        const int blk = blockIdx.x;
        const int b  = blk >> 8;            // / (N/64)
        const int n0 = (blk & 255) << 6;
        const float* fb = feats + (size_t)b * CC * NN + n0;
        {
            const int c0 = t >> 4;          // 0..15
            const int nq = (t & 15) * 4;
            #pragma unroll
            for (int pass = 0; pass < 4; ++pass) {
                const int c = c0 + pass * 16;
                const float4 v = *(const float4*)(fb + (size_t)c * NN + nq);
                tile[nq + 0][c] = v.x;
                tile[nq + 1][c] = v.y;
                tile[nq + 2][c] = v.z;
                tile[nq + 3][c] = v.w;
            }
        }
        __syncthreads();
        {
            float* ob = ftr + ((size_t)b * NN + n0) * CC;
            const int nb = t >> 4;          // 0..15
            const int c4 = (t & 15) * 4;
            #pragma unroll
            for (int pass = 0; pass < 4; ++pass) {
                const int n = nb + pass * 16;
                float4 v;
                v.x = tile[n][c4 + 0];
                v.y = tile[n][c4 + 1];
                v.z = tile[n][c4 + 2];
                v.w = tile[n][c4 + 3];
                *(float4*)(ob + (size_t)n * CC + c4) = v;
            }
        }
    } else {
        // ---- ball query: 4 waves, one query each, pipelined 512-pt chunks --
        const int wave = t >> 6;
        const int lane = t & 63;
        const int q    = (blockIdx.x - 2048) * 4 + wave;  // 0..8191
        const int b    = q >> 10;
        const int s    = q & (SS - 1);

        const float* xb = xyz + (size_t)b * NN * 3;
        const float qx = new_xyz[((size_t)b * SS + s) * 3 + 0];
        const float qy = new_xyz[((size_t)b * SS + s) * 3 + 1];
        const float qz = new_xyz[((size_t)b * SS + s) * 3 + 2];
        const unsigned long long below = (1ull << lane) - 1ull;

        float cx[8], cy[8], cz[8];
        #pragma unroll
        for (int j = 0; j < 8; ++j) {
            const int i = j * 64 + lane;
            cx[j] = xb[i * 3 + 0];
            cy[j] = xb[i * 3 + 1];
            cz[j] = xb[i * 3 + 2];
        }

        int count = 0;
        for (int base = 0; base < NN; base += 512) {
            // prefetch next chunk (loads in flight while we process current)
            float nx[8], ny[8], nz[8];
            const bool more = (base + 512) < NN;
            if (more) {
                #pragma unroll
                for (int j = 0; j < 8; ++j) {
                    const int i = base + 512 + j * 64 + lane;
                    nx[j] = xb[i * 3 + 0];
                    ny[j] = xb[i * 3 + 1];
                    nz[j] = xb[i * 3 + 2];
                }
            }
            // process current chunk
            #pragma unroll
            for (int j = 0; j < 8; ++j) {
                const float dx = qx - cx[j];
                const float dy = qy - cy[j];
                const float dz = qz - cz[j];
                // numpy order, no FMA contraction
                const float d2 = __fadd_rn(__fadd_rn(__fmul_rn(dx, dx),
                                                     __fmul_rn(dy, dy)),
                                           __fmul_rn(dz, dz));
                const bool within = d2 < R2;
                const unsigned long long m = __ballot(within);
                if (within) {
                    const int pos = count + __popcll(m & below);
                    if (pos < NSAMP) sidx[wave][pos] = base + j * 64 + lane;
                }
                count += __popcll(m);
            }
            if (count >= NSAMP) break;   // wave-uniform
            #pragma unroll
            for (int j = 0; j < 8; ++j) { cx[j] = nx[j]; cy[j] = ny[j]; cz[j] = nz[j]; }
        }
        __syncthreads();
        const int cnt = count < NSAMP ? count : NSAMP;
        const int first = (cnt > 0) ? sidx[wave][0] : 0;
        if (lane < NSAMP && lane >= cnt) sidx[wave][lane] = first;
        __syncthreads();

        if (lane < NSAMP) {
            const int k = lane;
            const int idx = sidx[wave][k];
            idxq[(size_t)q * NSAMP + k] = idx;
            // grouped_xyz -> out channels 0..2
            const float gx = xb[idx * 3 + 0] - qx;
            const float gy = xb[idx * 3 + 1] - qy;
            const float gz = xb[idx * 3 + 2] - qz;
            const size_t o = (((size_t)b * OUTCH + 0) * SS + s) * NSAMP + k;
            out[o + 0 * (size_t)SS * NSAMP] = gx;
            out[o + 1 * (size_t)SS * NSAMP] = gy;
            out[o + 2 * (size_t)SS * NSAMP] = gz;
        }
    }
}

// -------- kernel B: wave-autonomous gather, one 64-lane wave per query ------
__global__ __launch_bounds__(64) void gather_kernel(
    const float* __restrict__ ftr,      // (B,N,C)
    const int*   __restrict__ idxq,     // (B*S,32)
    float* __restrict__ out)            // (B,67,S,32)
{
    const int q = blockIdx.x;           // b*S+s
    const int b = q >> 10;
    const int s = q & (SS - 1);
    const int lane = threadIdx.x;

    __shared__ int   sidx[NSAMP];
    __shared__ float f[NSAMP][CC + 1];  // 65-pad: <=2-way banks (free)

    if (lane < NSAMP) sidx[lane] = idxq[(size_t)q * NSAMP + lane];
    __syncthreads();                    // single wave: compiles to waitcnt

    // stage: 16 lanes per sample row, float4 reads (256B per row, 4 rows/instr)
    {
        const float* fb = ftr + (size_t)b * NN * CC;
        const int k0 = lane >> 4;       // 0..3
        const int c4 = (lane & 15) * 4;
        #pragma unroll
        for (int pass = 0; pass < 8; ++pass) {
            const int k = k0 + pass * 4;
            const float4 v = *(const float4*)(fb + (size_t)sidx[k] * CC + c4);
            f[k][c4 + 0] = v.x;
            f[k][c4 + 1] = v.y;
            f[k][c4 + 2] = v.z;
            f[k][c4 + 3] = v.w;
        }
    }
    __syncthreads();

    // write: 8 lanes x float4-over-k per channel (128B segment), 8 ch/instr
    {
        const int k4 = (lane & 7) * 4;
        const int c0 = lane >> 3;       // 0..7
        #pragma unroll
        for (int pass = 0; pass < 8; ++pass) {
            const int c = c0 + pass * 8;
            float4 v;
            v.x = f[k4 + 0][c];
            v.y = f[k4 + 1][c];
            v.z = f[k4 + 2][c];
            v.w = f[k4 + 3][c];
            *(float4*)(out + (((size_t)b * OUTCH + 3 + c) * SS + s) * NSAMP + k4) = v;
        }
    }
}

// ---------------- fallback: R1 fused kernel (if ws too small) ----------------
__global__ __launch_bounds__(64) void qg_fused(
    const float* __restrict__ xyz, const float* __restrict__ new_xyz,
    const float* __restrict__ feats, float* __restrict__ out)
{
    const int bs   = blockIdx.x;
    const int b    = bs >> 10;
    const int s    = bs & (SS - 1);
    const int lane = threadIdx.x;

    const float* xb = xyz + (size_t)b * NN * 3;
    const float qx = new_xyz[((size_t)b * SS + s) * 3 + 0];
    const float qy = new_xyz[((size_t)b * SS + s) * 3 + 1];
    const float qz = new_xyz[((size_t)b * SS + s) * 3 + 2];

    __shared__ int sidx[NSAMP];
    int count = 0;
    for (int base = 0; base < NN; base += 64) {
        const int i = base + lane;
        const float dx = qx - xb[i * 3 + 0];
        const float dy = qy - xb[i * 3 + 1];
        const float dz = qz - xb[i * 3 + 2];
        const float d2 = __fadd_rn(__fadd_rn(__fmul_rn(dx, dx),
                                             __fmul_rn(dy, dy)),
                                   __fmul_rn(dz, dz));
        const bool within = d2 < R2;
        const unsigned long long m = __ballot(within);
        if (within) {
            const int pos = count + __popcll(m & ((1ull << lane) - 1ull));
            if (pos < NSAMP) sidx[pos] = i;
        }
        count += __popcll(m);
        if (count >= NSAMP) break;
    }
    __syncthreads();
    const int cnt = count < NSAMP ? count : NSAMP;
    const int first = (cnt > 0) ? sidx[0] : 0;
    if (lane < NSAMP && lane >= cnt) sidx[lane] = first;
    __syncthreads();

    const int k    = lane & 31;
    const int half = lane >> 5;
    const int idx  = sidx[k];
    const size_t obase = (((size_t)b * OUTCH + 0) * SS + s) * NSAMP + k;
    if (half == 0) {
        out[obase + 0 * (size_t)SS * NSAMP] = xb[idx * 3 + 0] - qx;
        out[obase + 1 * (size_t)SS * NSAMP] = xb[idx * 3 + 1] - qy;
        out[obase + 2 * (size_t)SS * NSAMP] = xb[idx * 3 + 2] - qz;
    }
    const float* fb = feats + (size_t)b * CC * NN;
    const size_t fo = (((size_t)b * OUTCH + 3) * SS + s) * NSAMP + k;
    for (int cch = half; cch < CC; cch += 2) {
        out[fo + (size_t)cch * SS * NSAMP] = fb[(size_t)cch * NN + idx];
    }
}

extern "C" void kernel_launch(void* const* d_in, const int* in_sizes, int n_in,
                              void* d_out, int out_size, void* d_ws, size_t ws_size,
                              hipStream_t stream) {
    const float* xyz     = (const float*)d_in[0];
    const float* new_xyz = (const float*)d_in[1];
    const float* feats   = (const float*)d_in[2];
    float* out           = (float*)d_out;

    const size_t ftr_bytes = (size_t)BB * NN * CC * sizeof(float);      // 33.5 MB
    const size_t idx_bytes = (size_t)BB * SS * NSAMP * sizeof(int);     // 1 MB

    if (ws_size >= ftr_bytes + idx_bytes) {
        float* ftr = (float*)d_ws;
        int* idxq  = (int*)((char*)d_ws + ftr_bytes);
        prep_kernel<<<4096, 256, 0, stream>>>(xyz, new_xyz, feats, ftr, idxq, out);
        gather_kernel<<<BB * SS, 64, 0, stream>>>(ftr, idxq, out);
    } else {
        qg_fused<<<BB * SS, 64, 0, stream>>>(xyz, new_xyz, feats, out);
    }
}

// Round 5
// 115.021 us; speedup vs baseline: 1.0621x; 1.0621x over previous
//
#include <hip/hip_runtime.h>

// QueryAndGroup: ball query (first 32 idx within radius, index order, padded
// with first hit) + grouped_xyz (xyz[idx]-center) + grouped feature gather.
// Shapes: xyz (8,16384,3) f32, new_xyz (8,1024,3) f32, features (8,64,16384) f32
// Out: (8, 3+64, 1024, 32) f32.
//
// R5: transpose ELIMINATED. One feature row feats[b,c,:] = 64KB = one LDS
// buffer. Gather kernel: one block per (b,c); stage the row in LDS (coalesced
// float4), gather by random LDS reads (~2-way bank cost, near-free m136),
// write out coalesced float4. Deletes the 67MB ftr round-trip of R3/R4.
// Traffic: feats 33.5MB read + out 70MB write + idx 1MB (+L2-hit re-reads).

#define BB 8
#define NN 16384
#define SS 1024
#define CC 64
#define NSAMP 32
#define OUTCH (3 + CC)

// float(0.04) to match numpy's weak-scalar promotion (NOT 0.2f*0.2f).
#define R2 0.04f

// ---------------- kernel A: ball query ----------------
// 4 waves/block, one query per wave, 512-pt chunks (loads batched ahead of
// the ballot phase -> one latency per chunk).
__global__ __launch_bounds__(256) void query_kernel(
    const float* __restrict__ xyz,      // (B,N,3)
    const float* __restrict__ new_xyz,  // (B,S,3)
    int* __restrict__ idxq,             // ws: (B*S,32)
    float* __restrict__ out)            // (B,67,S,32)
{
    __shared__ int sidx[4][NSAMP];

    const int t    = threadIdx.x;
    const int wave = t >> 6;
    const int lane = t & 63;
    const int q    = blockIdx.x * 4 + wave;   // 0..8191
    const int b    = q >> 10;
    const int s    = q & (SS - 1);

    const float* xb = xyz + (size_t)b * NN * 3;
    const float qx = new_xyz[((size_t)b * SS + s) * 3 + 0];
    const float qy = new_xyz[((size_t)b * SS + s) * 3 + 1];
    const float qz = new_xyz[((size_t)b * SS + s) * 3 + 2];
    const unsigned long long below = (1ull << lane) - 1ull;

    int count = 0;
    for (int base = 0; base < NN; base += 512) {
        float d2[8];
        #pragma unroll
        for (int j = 0; j < 8; ++j) {
            const int i = base + j * 64 + lane;
            const float dx = qx - xb[i * 3 + 0];
            const float dy = qy - xb[i * 3 + 1];
            const float dz = qz - xb[i * 3 + 2];
            // numpy order, no FMA contraction
            d2[j] = __fadd_rn(__fadd_rn(__fmul_rn(dx, dx),
                                        __fmul_rn(dy, dy)),
                              __fmul_rn(dz, dz));
        }
        #pragma unroll
        for (int j = 0; j < 8; ++j) {
            const bool within = d2[j] < R2;
            const unsigned long long m = __ballot(within);
            if (within) {
                const int pos = count + __popcll(m & below);
                if (pos < NSAMP) sidx[wave][pos] = base + j * 64 + lane;
            }
            count += __popcll(m);
        }
        if (count >= NSAMP) break;   // wave-uniform
    }
    __syncthreads();
    const int cnt = count < NSAMP ? count : NSAMP;
    const int first = (cnt > 0) ? sidx[wave][0] : 0;
    if (lane < NSAMP && lane >= cnt) sidx[wave][lane] = first;
    __syncthreads();

    if (lane < NSAMP) {
        const int k = lane;
        const int idx = sidx[wave][k];
        idxq[(size_t)q * NSAMP + k] = idx;
        // grouped_xyz -> out channels 0..2 (128B coalesced per channel)
        const float gx = xb[idx * 3 + 0] - qx;
        const float gy = xb[idx * 3 + 1] - qy;
        const float gz = xb[idx * 3 + 2] - qz;
        const size_t o = (((size_t)b * OUTCH + 0) * SS + s) * NSAMP + k;
        out[o + 0 * (size_t)SS * NSAMP] = gx;
        out[o + 1 * (size_t)SS * NSAMP] = gy;
        out[o + 2 * (size_t)SS * NSAMP] = gz;
    }
}

// ---------------- kernel B: row-in-LDS gather ----------------
// one block per (b,c): stage feats[b,c,:] (64KB) in LDS, gather via LDS,
// write out[b,3+c,:,:] (128KB) fully coalesced.
__global__ __launch_bounds__(512) void gather_kernel(
    const float* __restrict__ feats,    // (B,C,N)
    const int*   __restrict__ idxq,     // (B*S,32)
    float* __restrict__ out)            // (B,67,S,32)
{
    __shared__ float row[NN];           // 64 KB -> 2 blocks/CU

    const int c = blockIdx.x;           // 0..63
    const int b = blockIdx.y;           // 0..7
    const int t = threadIdx.x;          // 0..511

    // stage the full channel row, coalesced float4 (8 KB per wave-instr)
    const float* fr = feats + ((size_t)b * CC + c) * NN;
    #pragma unroll
    for (int i = 0; i < 8; ++i) {
        const int o = (i * 512 + t) * 4;
        *(float4*)(row + o) = *(const float4*)(fr + o);
    }
    __syncthreads();

    // gather: per iter, 512 threads cover 64 s x 32 k (8 lanes x 4k each)
    const int k4 = (t & 7) * 4;
    const int s0 = t >> 3;              // 0..63
    const int*  ib = idxq + (size_t)b * SS * NSAMP;
    float* ob = out + (((size_t)b * OUTCH + 3 + c) * SS) * NSAMP;
    #pragma unroll
    for (int it = 0; it < 16; ++it) {
        const int s = it * 64 + s0;
        const int4 id = *(const int4*)(ib + (size_t)s * NSAMP + k4);
        float4 v;
        v.x = row[id.x];
        v.y = row[id.y];
        v.z = row[id.z];
        v.w = row[id.w];
        *(float4*)(ob + (size_t)s * NSAMP + k4) = v;
    }
}

// ---------------- fallback: R1 fused kernel (if ws too small) ----------------
__global__ __launch_bounds__(64) void qg_fused(
    const float* __restrict__ xyz, const float* __restrict__ new_xyz,
    const float* __restrict__ feats, float* __restrict__ out)
{
    const int bs   = blockIdx.x;
    const int b    = bs >> 10;
    const int s    = bs & (SS - 1);
    const int lane = threadIdx.x;

    const float* xb = xyz + (size_t)b * NN * 3;
    const float qx = new_xyz[((size_t)b * SS + s) * 3 + 0];
    const float qy = new_xyz[((size_t)b * SS + s) * 3 + 1];
    const float qz = new_xyz[((size_t)b * SS + s) * 3 + 2];

    __shared__ int sidx[NSAMP];
    int count = 0;
    for (int base = 0; base < NN; base += 64) {
        const int i = base + lane;
        const float dx = qx - xb[i * 3 + 0];
        const float dy = qy - xb[i * 3 + 1];
        const float dz = qz - xb[i * 3 + 2];
        const float d2 = __fadd_rn(__fadd_rn(__fmul_rn(dx, dx),
                                             __fmul_rn(dy, dy)),
                                   __fmul_rn(dz, dz));
        const bool within = d2 < R2;
        const unsigned long long m = __ballot(within);
        if (within) {
            const int pos = count + __popcll(m & ((1ull << lane) - 1ull));
            if (pos < NSAMP) sidx[pos] = i;
        }
        count += __popcll(m);
        if (count >= NSAMP) break;
    }
    __syncthreads();
    const int cnt = count < NSAMP ? count : NSAMP;
    const int first = (cnt > 0) ? sidx[0] : 0;
    if (lane < NSAMP && lane >= cnt) sidx[lane] = first;
    __syncthreads();

    const int k    = lane & 31;
    const int half = lane >> 5;
    const int idx  = sidx[k];
    const size_t obase = (((size_t)b * OUTCH + 0) * SS + s) * NSAMP + k;
    if (half == 0) {
        out[obase + 0 * (size_t)SS * NSAMP] = xb[idx * 3 + 0] - qx;
        out[obase + 1 * (size_t)SS * NSAMP] = xb[idx * 3 + 1] - qy;
        out[obase + 2 * (size_t)SS * NSAMP] = xb[idx * 3 + 2] - qz;
    }
    const float* fb = feats + (size_t)b * CC * NN;
    const size_t fo = (((size_t)b * OUTCH + 3) * SS + s) * NSAMP + k;
    for (int cch = half; cch < CC; cch += 2) {
        out[fo + (size_t)cch * SS * NSAMP] = fb[(size_t)cch * NN + idx];
    }
}

extern "C" void kernel_launch(void* const* d_in, const int* in_sizes, int n_in,
                              void* d_out, int out_size, void* d_ws, size_t ws_size,
                              hipStream_t stream) {
    const float* xyz     = (const float*)d_in[0];
    const float* new_xyz = (const float*)d_in[1];
    const float* feats   = (const float*)d_in[2];
    float* out           = (float*)d_out;

    const size_t idx_bytes = (size_t)BB * SS * NSAMP * sizeof(int);     // 1 MB

    if (ws_size >= idx_bytes) {
        int* idxq = (int*)d_ws;
        query_kernel<<<2048, 256, 0, stream>>>(xyz, new_xyz, idxq, out);
        gather_kernel<<<dim3(CC, BB), 512, 0, stream>>>(feats, idxq, out);
    } else {
        qg_fused<<<BB * SS, 64, 0, stream>>>(xyz, new_xyz, feats, out);
    }
}